// Round 10
// baseline (6593.137 us; speedup 1.0000x reference)
//
#include <hip/hip_runtime.h>
#include <hip/hip_bf16.h>
#include <math.h>

#define BQ 64
#define TENC_ 512
#define TDEC_ 64
#define HH 1024
#define VV 1024
#define AA 512

typedef short v8s __attribute__((ext_vector_type(8)));
typedef float v4f __attribute__((ext_vector_type(4)));
typedef unsigned short u16;

__device__ __forceinline__ u16 f2bf(float f) {
    unsigned u = __builtin_bit_cast(unsigned, f);
    u = u + 0x7FFFu + ((u >> 16) & 1u);
    return (u16)(u >> 16);
}
__device__ __forceinline__ float bf2f(u16 h) {
    unsigned u = ((unsigned)h) << 16;
    return __builtin_bit_cast(float, u);
}
__device__ __forceinline__ uint4 pack8(const float4 a, const float4 b) {
    uint4 o;
    o.x = (unsigned)f2bf(a.x) | ((unsigned)f2bf(a.y) << 16);
    o.y = (unsigned)f2bf(a.z) | ((unsigned)f2bf(a.w) << 16);
    o.z = (unsigned)f2bf(b.x) | ((unsigned)f2bf(b.y) << 16);
    o.w = (unsigned)f2bf(b.z) | ((unsigned)f2bf(b.w) << 16);
    return o;
}

// ---------------- conversion / packing kernels ----------------

__global__ void conv_f2b(const float* __restrict__ src, u16* __restrict__ dst, int n8) {
    int i = blockIdx.x * 256 + threadIdx.x;
    if (i >= n8) return;
    ((uint4*)dst)[i] = pack8(*(const float4*)(src + (size_t)i * 8),
                             *(const float4*)(src + (size_t)i * 8 + 4));
}

// Fused-LSTM weight pack, wave-contiguous:
// wpk2[i], i = bid*4096 + c*512 + ks*64 + lane  (uint4 units; 8 bf16 each)
//   packed row = bid*16 + (lane&15); r=(lane&15); gate=r>>2; uu=r&3; orig=gate*1024+bid*4+uu
//   col = c*256 + ks*32 + (lane>>4)*8 ;  col<1024 -> wih, else whh
__global__ void pack_g2(const float* __restrict__ wih, const float* __restrict__ whh,
                        const float* __restrict__ bih, const float* __restrict__ bhh,
                        u16* __restrict__ wpk2, float* __restrict__ bpk2) {
    int i = blockIdx.x * 256 + threadIdx.x;          // 1M uint4 chunks
    int lane = i & 63, ks = (i >> 6) & 7, c = (i >> 9) & 7, bid = i >> 12;
    int r = lane & 15, gate = r >> 2, uu = r & 3;
    int orig = gate * 1024 + bid * 4 + uu;
    int col = c * 256 + ks * 32 + (lane >> 4) * 8;
    const float* s = (col < 1024) ? wih + (size_t)orig * 1024 + col
                                  : whh + (size_t)orig * 1024 + (col - 1024);
    ((uint4*)wpk2)[i] = pack8(*(const float4*)s, *(const float4*)(s + 4));
    if (col == 0) bpk2[bid * 16 + r] = bih[orig] + bhh[orig];
}

// q weights packed for gemm_step: kcN=2, nB<8
__global__ void pack_qw(const float* __restrict__ wq, u16* __restrict__ qpk) {
    int i = blockIdx.x * 256 + threadIdx.x;          // 65536
    int lane = i & 63, ks = (i >> 6) & 15, kc = (i >> 10) & 1, w = (i >> 11) & 3, nB = i >> 13;
    int row = nB * 64 + w * 16 + (lane & 15);
    int col = kc * 512 + ks * 32 + (lane >> 4) * 8;
    const float* s = wq + (size_t)row * 1024 + col;
    ((uint4*)qpk)[i] = pack8(*(const float4*)s, *(const float4*)(s + 4));
}

// stacked K/V projection weights [1024][1024]: rows<512 = wk, else wv
__global__ void stack_kv(const float* __restrict__ wk, const float* __restrict__ wv,
                         u16* __restrict__ dst) {
    int i = blockIdx.x * 256 + threadIdx.x;          // 131072
    int row = i >> 7, k = (i & 127) * 8;
    const float* s = (row < 512) ? wk + (size_t)row * 1024 + k
                                 : wv + (size_t)(row - 512) * 1024 + k;
    ((uint4*)dst)[i] = pack8(*(const float4*)s, *(const float4*)(s + 4));
}
__global__ void stack_bias(const float* __restrict__ bk, const float* __restrict__ bv,
                           float* __restrict__ dst) {
    int i = blockIdx.x * 256 + threadIdx.x;
    if (i < 512) dst[i] = bk[i]; else if (i < 1024) dst[i] = bv[i - 512];
}

__global__ void embed_k(const int* __restrict__ tgt, const float* __restrict__ table,
                        u16* __restrict__ Eb) {
    int bid = blockIdx.x;            // t*64 + b
    int t = bid >> 6, b = bid & 63;
    int tok = (t == 0) ? 0 : tgt[b * TDEC_ + t - 1];
    int lane = threadIdx.x;
    const float* src = table + (size_t)tok * AA + lane * 8;
    ((uint4*)Eb)[(size_t)bid * 64 + lane] = pack8(*(const float4*)src, *(const float4*)(src + 4));
}

// ---------------- big MFMA GEMM: 128x128 tile, XCD-chunked swizzle ----------------
// OUT: 1=bf16+bias, 2=f32+bias w/ (t*64+b)->(b*64+t) remap, 6=bf16+bias split to out/out2
template<int OUT, bool AF32>
__global__ __launch_bounds__(256) void gemm_big(
    const void* __restrict__ Av, int lda,
    const u16* __restrict__ W, int ldw,
    const float* __restrict__ bias,
    void* __restrict__ outv, void* __restrict__ outv2, int ldo, int K) {
    __shared__ u16 As[128 * 128];
    __shared__ u16 Ws[128 * 128];
    const int tid = threadIdx.x;
    const int w = tid >> 6, lane = tid & 63;
    const int wm = w >> 1, wn = w & 1;
    const int li = lane & 15, lg = lane >> 4;
    const int nwg = gridDim.x * gridDim.y;
    const int flat = blockIdx.y * gridDim.x + blockIdx.x;
    const int nf = (flat & 7) * (nwg >> 3) + (flat >> 3);
    const int mB = (nf / gridDim.x) * 128, nB = (nf % gridDim.x) * 128;
    v4f acc[4][4];
    #pragma unroll
    for (int mt = 0; mt < 4; ++mt)
        #pragma unroll
        for (int nt = 0; nt < 4; ++nt) acc[mt][nt] = (v4f){0.f, 0.f, 0.f, 0.f};
    for (int kc = 0; kc < K; kc += 128) {
        for (int it = 0; it < 8; ++it) {
            int flat2 = it * 256 + tid;
            int row = flat2 >> 4, c8 = flat2 & 15;
            uint4 val;
            if (AF32) {
                const float* Af = (const float*)Av + (size_t)(mB + row) * lda + kc + c8 * 8;
                val = pack8(*(const float4*)Af, *(const float4*)(Af + 4));
            } else {
                val = *(const uint4*)((const u16*)Av + (size_t)(mB + row) * lda + kc + c8 * 8);
            }
            int byte = (row * 256 + c8 * 16) ^ ((row & 7) << 4);
            *(uint4*)((char*)As + byte) = val;
            uint4 wv2 = *(const uint4*)(W + (size_t)(nB + row) * ldw + kc + c8 * 8);
            *(uint4*)((char*)Ws + byte) = wv2;
        }
        __syncthreads();
        for (int ks = 0; ks < 4; ++ks) {
            v8s wf[4];
            #pragma unroll
            for (int nt = 0; nt < 4; ++nt) {
                int row = wn * 64 + nt * 16 + li;
                int byte = (row * 256 + ks * 64 + lg * 16) ^ ((row & 7) << 4);
                wf[nt] = *(const v8s*)((char*)Ws + byte);
            }
            #pragma unroll
            for (int mt = 0; mt < 4; ++mt) {
                int row = wm * 64 + mt * 16 + li;
                int byte = (row * 256 + ks * 64 + lg * 16) ^ ((row & 7) << 4);
                v8s af = *(const v8s*)((char*)As + byte);
                #pragma unroll
                for (int nt = 0; nt < 4; ++nt)
                    acc[mt][nt] = __builtin_amdgcn_mfma_f32_16x16x32_bf16(af, wf[nt], acc[mt][nt], 0, 0, 0);
            }
        }
        __syncthreads();
    }
    #pragma unroll
    for (int mt = 0; mt < 4; ++mt) {
        #pragma unroll
        for (int r = 0; r < 4; ++r) {
            int m = mB + wm * 64 + mt * 16 + lg * 4 + r;
            #pragma unroll
            for (int nt = 0; nt < 4; ++nt) {
                int n = nB + wn * 64 + nt * 16 + li;
                float v = acc[mt][nt][r] + bias[n];
                if (OUT == 1) {
                    ((u16*)outv)[(size_t)m * ldo + n] = f2bf(v);
                } else if (OUT == 2) {
                    int mm = (m & 63) * TDEC_ + (m >> 6);
                    ((float*)outv)[(size_t)mm * ldo + n] = v;
                } else {
                    if (n < 512) ((u16*)outv)[(size_t)m * 512 + n] = f2bf(v);
                    else         ((u16*)outv2)[(size_t)m * 512 + (n - 512)] = f2bf(v);
                }
            }
        }
    }
}

// ---------------- fused LSTM: full-K gates GEMM + cell epilogue ----------------
// 256 blocks x 256 threads. Block bid owns units [bid*4, bid*4+4) = packed rows [bid*16,+16).
// M=64, N=16, K=2048 in 8 chunks of 256. A double-buffered in LDS; W wave-contiguous (wpk2).
// PHASE 0: A = [Eb_t (512) | attnb (512) | h0prev (1024)];  PHASE 1: A = [h0cur | h1prev]
template<int PHASE>
__global__ __launch_bounds__(256) void lstm_fc(
    const u16* __restrict__ p0, const u16* __restrict__ p1, const u16* __restrict__ p2,
    const u16* __restrict__ wpk2, const float* __restrict__ bpk2,
    float* __restrict__ cst, u16* __restrict__ hout, u16* __restrict__ h1a_t)
{
    __shared__ __align__(16) char smem[65536];
    const int tid = threadIdx.x, bid = blockIdx.x;
    const int lane = tid & 63, li = lane & 15, lg = lane >> 4, w = tid >> 6;

    auto srcp = [&](int c, int row, int k2) -> const u16* {
        int k = c * 256 + k2;
        if (PHASE == 0) {
            if (k < 512)  return p0 + row * 512 + k;
            if (k < 1024) return p1 + row * 512 + (k - 512);
            return p2 + row * 1024 + (k - 1024);
        } else {
            if (k < 1024) return p0 + row * 1024 + k;
            return p1 + row * 1024 + (k - 1024);
        }
    };
    uint4 rg[8];
    auto loadc = [&](int c) {
        #pragma unroll
        for (int it = 0; it < 8; ++it) {
            int flat = it * 256 + tid, row = flat >> 5, c16 = flat & 31;
            rg[it] = *(const uint4*)srcp(c, row, c16 * 8);
        }
    };
    auto writec = [&](int c) {
        char* buf = smem + (c & 1) * 32768;
        #pragma unroll
        for (int it = 0; it < 8; ++it) {
            int flat = it * 256 + tid, row = flat >> 5, c16 = flat & 31;
            int byte = (row * 512 + c16 * 16) ^ ((row & 7) << 4);
            *(uint4*)(buf + byte) = rg[it];
        }
    };

    loadc(0); writec(0); __syncthreads();
    v4f acc = (v4f){0.f, 0.f, 0.f, 0.f};
    const u16* wp = wpk2 + (size_t)bid * 32768;       // bid*4096 uint4 = 32768 u16
    const int arow = w * 16 + li;
    for (int c = 0; c < 8; ++c) {
        if (c < 7) loadc(c + 1);
        char* buf = smem + (c & 1) * 32768;
        const u16* wc = wp + c * 4096;                // c*512 uint4
        #pragma unroll
        for (int ks = 0; ks < 8; ++ks) {
            v8s wf = *(const v8s*)(wc + ks * 512 + lane * 8);
            int byte = (arow * 512 + ks * 64 + lg * 16) ^ ((arow & 7) << 4);
            v8s af = *(const v8s*)(buf + byte);
            acc = __builtin_amdgcn_mfma_f32_16x16x32_bf16(af, wf, acc, 0, 0, 0);
        }
        if (c < 7) writec(c + 1);
        __syncthreads();
    }
    // gates -> LDS [64][17] f32 (col = packed row index), then cell
    float* gl = (float*)smem;
    #pragma unroll
    for (int r = 0; r < 4; ++r)
        gl[(w * 16 + lg * 4 + r) * 17 + li] = acc[r];
    __syncthreads();
    {
        int m = tid & 63, uu = tid >> 6;              // 64 batches x 4 units
        float gi = gl[m * 17 + uu]      + bpk2[bid * 16 + uu];
        float gf = gl[m * 17 + 4 + uu]  + bpk2[bid * 16 + 4 + uu];
        float gg = gl[m * 17 + 8 + uu]  + bpk2[bid * 16 + 8 + uu];
        float go = gl[m * 17 + 12 + uu] + bpk2[bid * 16 + 12 + uu];
        int ci = m * 1024 + bid * 4 + uu;
        float ii = 1.f / (1.f + expf(-gi));
        float ff = 1.f / (1.f + expf(-gf));
        float oo = 1.f / (1.f + expf(-go));
        float c2 = ff * cst[ci] + ii * tanhf(gg);
        float hv = oo * tanhf(c2);
        cst[ci] = c2;
        hout[ci] = f2bf(hv);
        if (PHASE == 1) h1a_t[ci] = f2bf(hv);
    }
}

// ---------------- per-step MFMA GEMM (q projection; packed W) ----------------
__global__ __launch_bounds__(256) void gemm_step(
    const u16* A0, const u16* A1,
    int l0, int l1,
    const u16* __restrict__ wpk, int kcN,
    float* __restrict__ gp, int N) {
    __shared__ u16 As[64 * 512];
    const int tid = threadIdx.x;
    const int kc = blockIdx.y;
    const u16* A = (kc == 0) ? A0 : A1;
    const int lda = (kc == 0) ? l0 : l1;
    for (int it = 0; it < 16; ++it) {
        int flat = it * 256 + tid;
        int row = flat >> 6, c8 = flat & 63;
        uint4 v = *(const uint4*)(A + (size_t)row * lda + c8 * 8);
        int byte = (row * 1024 + c8 * 16) ^ ((row & 7) << 4);
        *(uint4*)((char*)As + byte) = v;
    }
    __syncthreads();
    const int w = tid >> 6, lane = tid & 63;
    const int li = lane & 15, lg = lane >> 4;
    const u16* Wp = wpk + (size_t)((blockIdx.x * 4 + w) * kcN + kc) * 8192 + lane * 8;
    v4f acc[4];
    #pragma unroll
    for (int mt = 0; mt < 4; ++mt) acc[mt] = (v4f){0.f, 0.f, 0.f, 0.f};
    for (int ks = 0; ks < 16; ++ks) {
        v8s wf = *(const v8s*)(Wp + ks * 512);
        #pragma unroll
        for (int mt = 0; mt < 4; ++mt) {
            int row = mt * 16 + li;
            int byte = (row * 1024 + ks * 64 + lg * 16) ^ ((row & 7) << 4);
            v8s af = *(const v8s*)((char*)As + byte);
            acc[mt] = __builtin_amdgcn_mfma_f32_16x16x32_bf16(af, wf, acc[mt], 0, 0, 0);
        }
    }
    const int col = blockIdx.x * 64 + w * 16 + li;
    float* g = gp + (size_t)kc * 64 * N;
    #pragma unroll
    for (int mt = 0; mt < 4; ++mt)
        #pragma unroll
        for (int r = 0; r < 4; ++r)
            g[(size_t)(mt * 16 + lg * 4 + r) * N + col] = acc[mt][r];
}

// ---------------- scores (bf16 K): sraw[b][t] = dot(Kb[b,t,:], q[b,:]) ----------------
__global__ __launch_bounds__(256) void scores_k(
    const u16* __restrict__ Kb, const float* __restrict__ qp,
    const float* __restrict__ bq, float* __restrict__ sraw) {
    __shared__ float qs[AA];
    int b = blockIdx.x, tc = blockIdx.y, tid = threadIdx.x;
    for (int a = tid; a < AA; a += 256)
        qs[a] = qp[(size_t)b * AA + a] + qp[(size_t)(64 + b) * AA + a] + bq[a];
    __syncthreads();
    int w = tid >> 6, lane = tid & 63, lg = lane >> 4, li = lane & 15;
    for (int sub = 0; sub < 4; ++sub) {
        int t = tc * 64 + w * 16 + sub * 4 + lg;
        const u16* kr = Kb + ((size_t)b * TENC_ + t) * AA + li * 32;
        float s = 0.f;
        #pragma unroll
        for (int j = 0; j < 4; ++j) {
            uint4 v = *(const uint4*)(kr + j * 8);
            const u16* pv = (const u16*)&v;
            #pragma unroll
            for (int e = 0; e < 8; ++e) s = fmaf(bf2f(pv[e]), qs[li * 32 + j * 8 + e], s);
        }
        s += __shfl_xor(s, 1); s += __shfl_xor(s, 2);
        s += __shfl_xor(s, 4); s += __shfl_xor(s, 8);
        if (li == 0) sraw[(size_t)b * TENC_ + t] = s;
    }
}

// ---------------- softmax + attn.V (bf16 V) ----------------
__global__ __launch_bounds__(256) void attnout_k(
    const float* __restrict__ sraw, const u16* __restrict__ Vb, u16* __restrict__ attnb) {
    __shared__ float red[256];
    __shared__ float p[TENC_];
    __shared__ float accs[4][128];
    int b = blockIdx.x, a0 = blockIdx.y * 128, tid = threadIdx.x;
    float s0 = sraw[(size_t)b * TENC_ + tid], s1 = sraw[(size_t)b * TENC_ + 256 + tid];
    red[tid] = fmaxf(s0, s1);
    __syncthreads();
    for (int off = 128; off; off >>= 1) {
        if (tid < off) red[tid] = fmaxf(red[tid], red[tid + off]);
        __syncthreads();
    }
    float m = red[0];
    __syncthreads();
    float e0 = expf(s0 - m), e1 = expf(s1 - m);
    red[tid] = e0 + e1;
    __syncthreads();
    for (int off = 128; off; off >>= 1) {
        if (tid < off) red[tid] += red[tid + off];
        __syncthreads();
    }
    float inv = 1.f / red[0];
    p[tid] = e0 * inv; p[tid + 256] = e1 * inv;
    __syncthreads();
    int w = tid >> 6, lane = tid & 63;
    float a0f = 0.f, a1f = 0.f;
    for (int t = w; t < TENC_; t += 4) {
        unsigned v = *(const unsigned*)(Vb + ((size_t)b * TENC_ + t) * AA + a0 + lane * 2);
        float pw = p[t];
        a0f += pw * bf2f((u16)(v & 0xFFFF));
        a1f += pw * bf2f((u16)(v >> 16));
    }
    accs[w][lane * 2] = a0f; accs[w][lane * 2 + 1] = a1f;
    __syncthreads();
    if (tid < 128) {
        float s = accs[0][tid] + accs[1][tid] + accs[2][tid] + accs[3][tid];
        attnb[(size_t)b * AA + a0 + tid] = f2bf(s);
    }
}

// ---------------- LayerNorm+ReLU, bf16 in-place ----------------
__global__ __launch_bounds__(256) void ln_relu_b(u16* __restrict__ x, const float* __restrict__ g,
                                                 const float* __restrict__ bb) {
    int row = blockIdx.x, tid = threadIdx.x;
    u16* xr = x + (size_t)row * 2048;
    __shared__ float red[256];
    uint4 v = *(const uint4*)(xr + tid * 8);
    const u16* pv = (const u16*)&v;
    float lv[8];
    float s = 0.f;
    #pragma unroll
    for (int e = 0; e < 8; ++e) { lv[e] = bf2f(pv[e]); s += lv[e]; }
    red[tid] = s;
    __syncthreads();
    for (int off = 128; off; off >>= 1) {
        if (tid < off) red[tid] += red[tid + off];
        __syncthreads();
    }
    float mu = red[0] * (1.f / 2048.f);
    __syncthreads();
    s = 0.f;
    #pragma unroll
    for (int e = 0; e < 8; ++e) { float d = lv[e] - mu; s += d * d; }
    red[tid] = s;
    __syncthreads();
    for (int off = 128; off; off >>= 1) {
        if (tid < off) red[tid] += red[tid + off];
        __syncthreads();
    }
    float inv = rsqrtf(red[0] * (1.f / 2048.f) + 1e-5f);
    const float4 g1 = *(const float4*)(g + tid * 8), g2 = *(const float4*)(g + tid * 8 + 4);
    const float4 b1 = *(const float4*)(bb + tid * 8), b2 = *(const float4*)(bb + tid * 8 + 4);
    float gv[8] = {g1.x, g1.y, g1.z, g1.w, g2.x, g2.y, g2.z, g2.w};
    float bv[8] = {b1.x, b1.y, b1.z, b1.w, b2.x, b2.y, b2.z, b2.w};
    float o[8];
    #pragma unroll
    for (int e = 0; e < 8; ++e) o[e] = fmaxf((lv[e] - mu) * inv * gv[e] + bv[e], 0.f);
    *(uint4*)(xr + tid * 8) = pack8(make_float4(o[0], o[1], o[2], o[3]),
                                    make_float4(o[4], o[5], o[6], o[7]));
}

// ---------------- loss ----------------
__global__ void ce_loss(const float* __restrict__ logits, const int* __restrict__ target,
                        float* __restrict__ acc) {
    const int r = blockIdx.x;
    const float* row = logits + (size_t)r * VV;
    const int tid = threadIdx.x;
    __shared__ float red[256];
    float lv[4];
    float m = -1e30f;
    #pragma unroll
    for (int i = 0; i < 4; ++i) { lv[i] = row[tid + i * 256]; m = fmaxf(m, lv[i]); }
    red[tid] = m;
    __syncthreads();
    for (int off = 128; off; off >>= 1) {
        if (tid < off) red[tid] = fmaxf(red[tid], red[tid + off]);
        __syncthreads();
    }
    m = red[0];
    __syncthreads();
    float s = 0.f;
    #pragma unroll
    for (int i = 0; i < 4; ++i) s += expf(lv[i] - m);
    red[tid] = s;
    __syncthreads();
    for (int off = 128; off; off >>= 1) {
        if (tid < off) red[tid] += red[tid + off];
        __syncthreads();
    }
    if (tid == 0) {
        const float nll = logf(red[0]) + m - row[target[r]];
        atomicAdd(acc, nll);
    }
}

__global__ void finalize_loss(const float* __restrict__ acc, float* __restrict__ out) {
    out[0] = acc[0] * (1.f / 4096.f);
}

// ---------------- host ----------------
extern "C" void kernel_launch(void* const* d_in, const int* in_sizes, int n_in,
                              void* d_out, int out_size, void* d_ws, size_t ws_size,
                              hipStream_t stream) {
    const float* enc       = (const float*)d_in[0];
    const int*   target    = (const int*)d_in[1];
    const float* emb_table = (const float*)d_in[2];
    const float* att_wq    = (const float*)d_in[3];
    const float* att_bq    = (const float*)d_in[4];
    const float* att_wk    = (const float*)d_in[5];
    const float* att_bk    = (const float*)d_in[6];
    const float* att_wv    = (const float*)d_in[7];
    const float* att_bv    = (const float*)d_in[8];
    const float* w_ih0     = (const float*)d_in[9];
    const float* w_hh0     = (const float*)d_in[10];
    const float* b_ih0     = (const float*)d_in[11];
    const float* b_hh0     = (const float*)d_in[12];
    const float* w_ih1     = (const float*)d_in[13];
    const float* w_hh1     = (const float*)d_in[14];
    const float* b_ih1     = (const float*)d_in[15];
    const float* b_hh1     = (const float*)d_in[16];
    const float* mlp_w1    = (const float*)d_in[17];
    const float* mlp_b1    = (const float*)d_in[18];
    const float* ln_g      = (const float*)d_in[19];
    const float* ln_b      = (const float*)d_in[20];
    const float* mlp_w2    = (const float*)d_in[21];
    const float* mlp_b2    = (const float*)d_in[22];
    float* out = (float*)d_out;
    char* ws = (char*)d_ws;

    size_t off = 0;
    auto alloc = [&](size_t bytes) { size_t o = off; off += (bytes + 255) & ~(size_t)255; return o; };
    u16*   Kb    = (u16*)(ws + alloc((size_t)BQ * TENC_ * AA * 2));
    u16*   Vb    = (u16*)(ws + alloc((size_t)BQ * TENC_ * AA * 2));
    u16*   Eb    = (u16*)(ws + alloc((size_t)TDEC_ * BQ * AA * 2));
    u16*   wpk0  = (u16*)(ws + alloc((size_t)4096 * 2048 * 2));
    u16*   wpk1  = (u16*)(ws + alloc((size_t)4096 * 2048 * 2));
    float* bpk0  = (float*)(ws + alloc(4096 * 4));
    float* bpk1  = (float*)(ws + alloc(4096 * 4));
    u16*   qpk   = (u16*)(ws + alloc((size_t)512 * 1024 * 2));
    u16*   wkv   = (u16*)(ws + alloc((size_t)1024 * 1024 * 2));
    float* bkv   = (float*)(ws + alloc(1024 * 4));
    u16*   w1b   = (u16*)(ws + alloc((size_t)2 * VV * HH * 2));
    u16*   w2b   = (u16*)(ws + alloc((size_t)VV * 2 * VV * 2));
    float* qp    = (float*)(ws + alloc((size_t)2 * 64 * 512 * 4));
    float* sraw  = (float*)(ws + alloc((size_t)BQ * TENC_ * 4));
    u16*   h0b   = (u16*)(ws + alloc((size_t)2 * BQ * HH * 2));      // parity double-buffered
    u16*   h1b   = (u16*)(ws + alloc((size_t)2 * BQ * HH * 2));
    u16*   attnb = (u16*)(ws + alloc((size_t)BQ * AA * 2));
    float* c0    = (float*)(ws + alloc((size_t)BQ * HH * 4));
    float* c1    = (float*)(ws + alloc((size_t)BQ * HH * 4));
    u16*   h1a   = (u16*)(ws + alloc((size_t)TDEC_ * BQ * HH * 2));
    u16*   x1b   = (u16*)(ws + alloc((size_t)TDEC_ * BQ * 2 * VV * 2));
    float* lacc  = (float*)(ws + alloc(256));

    // ---- prologue: weight packing/conversion ----
    pack_g2<<<4096, 256, 0, stream>>>(w_ih0, w_hh0, b_ih0, b_hh0, wpk0, bpk0);
    pack_g2<<<4096, 256, 0, stream>>>(w_ih1, w_hh1, b_ih1, b_hh1, wpk1, bpk1);
    pack_qw<<<256, 256, 0, stream>>>(att_wq, qpk);
    stack_kv<<<512, 256, 0, stream>>>(att_wk, att_wv, wkv);
    stack_bias<<<4, 256, 0, stream>>>(att_bk, att_bv, bkv);
    conv_f2b<<<1024, 256, 0, stream>>>(mlp_w1, w1b, 2 * VV * HH / 8);
    conv_f2b<<<1024, 256, 0, stream>>>(mlp_w2, w2b, VV * 2 * VV / 8);
    embed_k<<<TDEC_ * BQ, 64, 0, stream>>>(target, emb_table, Eb);

    hipMemsetAsync(h0b, 0, (size_t)2 * BQ * HH * 2, stream);
    hipMemsetAsync(h1b, 0, (size_t)2 * BQ * HH * 2, stream);
    hipMemsetAsync(attnb, 0, (size_t)BQ * AA * 2, stream);
    hipMemsetAsync(c0, 0, (size_t)BQ * HH * 4, stream);
    hipMemsetAsync(c1, 0, (size_t)BQ * HH * 4, stream);
    hipMemsetAsync(lacc, 0, 4, stream);

    // merged K/V projection: [32768,1024] = enc @ [wk;wv]^T -> bf16 Kb | Vb
    gemm_big<6, true><<<dim3(8, 256), 256, 0, stream>>>(enc, HH, wkv, HH, bkv, Kb, Vb, 512, HH);

    // ---- recurrence: 5 launches/step ----
    for (int t = 0; t < TDEC_; ++t) {
        const int cur = t & 1, prv = cur ^ 1;
        const u16* h0p = h0b + prv * (BQ * HH);
        u16*       h0c = h0b + cur * (BQ * HH);
        const u16* h1p = h1b + prv * (BQ * HH);
        u16*       h1c = h1b + cur * (BQ * HH);
        const u16* et  = Eb + (size_t)t * BQ * AA;
        lstm_fc<0><<<256, 256, 0, stream>>>(et, attnb, h0p, wpk0, bpk0, c0, h0c, nullptr);
        lstm_fc<1><<<256, 256, 0, stream>>>(h0c, h1p, nullptr, wpk1, bpk1, c1, h1c,
                                            h1a + (size_t)t * BQ * HH);
        if (t < TDEC_ - 1) {
            gemm_step<<<dim3(8, 2), 256, 0, stream>>>(
                h1c, h1c + 512, HH, HH, qpk, 2, qp, 512);
            scores_k<<<dim3(64, 8), 256, 0, stream>>>(Kb, qp, att_bq, sraw);
            attnout_k<<<dim3(64, 4), 256, 0, stream>>>(sraw, Vb, attnb);
        }
    }

    // ---- batched MLP head ----
    gemm_big<1, false><<<dim3(16, 32), 256, 0, stream>>>(h1a, HH, w1b, HH, mlp_b1, x1b, nullptr, 2 * VV, HH);
    ln_relu_b<<<TDEC_ * BQ, 256, 0, stream>>>(x1b, ln_g, ln_b);
    gemm_big<2, false><<<dim3(8, 32), 256, 0, stream>>>(x1b, 2 * VV, w2b, 2 * VV, mlp_b2, out, nullptr, VV, 2 * VV);

    ce_loss<<<BQ * TDEC_, 256, 0, stream>>>(out, target, lacc);
    finalize_loss<<<1, 1, 0, stream>>>(lacc, out + (size_t)BQ * TDEC_ * VV);
}

// Round 11
// 4676.168 us; speedup vs baseline: 1.4099x; 1.4099x over previous
//
#include <hip/hip_runtime.h>
#include <hip/hip_bf16.h>
#include <math.h>

#define BQ 64
#define TENC_ 512
#define TDEC_ 64
#define HH 1024
#define VV 1024
#define AA 512

typedef short v8s __attribute__((ext_vector_type(8)));
typedef float v4f __attribute__((ext_vector_type(4)));
typedef unsigned short u16;

__device__ __forceinline__ u16 f2bf(float f) {
    unsigned u = __builtin_bit_cast(unsigned, f);
    u = u + 0x7FFFu + ((u >> 16) & 1u);
    return (u16)(u >> 16);
}
__device__ __forceinline__ float bf2f(u16 h) {
    unsigned u = ((unsigned)h) << 16;
    return __builtin_bit_cast(float, u);
}
__device__ __forceinline__ uint4 pack8(const float4 a, const float4 b) {
    uint4 o;
    o.x = (unsigned)f2bf(a.x) | ((unsigned)f2bf(a.y) << 16);
    o.y = (unsigned)f2bf(a.z) | ((unsigned)f2bf(a.w) << 16);
    o.z = (unsigned)f2bf(b.x) | ((unsigned)f2bf(b.y) << 16);
    o.w = (unsigned)f2bf(b.z) | ((unsigned)f2bf(b.w) << 16);
    return o;
}

// ---------------- conversion / packing kernels ----------------

__global__ void conv_f2b(const float* __restrict__ src, u16* __restrict__ dst, int n8) {
    int i = blockIdx.x * 256 + threadIdx.x;
    if (i >= n8) return;
    ((uint4*)dst)[i] = pack8(*(const float4*)(src + (size_t)i * 8),
                             *(const float4*)(src + (size_t)i * 8 + 4));
}

// gates weights packed in wave consumption order:
// wpk[((nB*4+w)*4+kc)*8192 + ks*512 + lane*8 + e] = W[nB*64+w*16+(lane&15)][kc*512+ks*32+(lane>>4)*8+e]
// where W cols [0,1024) = wih, [1024,2048) = whh
__global__ void pack_g(const float* __restrict__ wih, const float* __restrict__ whh,
                       u16* __restrict__ wpk) {
    int i = blockIdx.x * 256 + threadIdx.x;
    int lane = i & 63, ks = (i >> 6) & 15, kc = (i >> 10) & 3, w = (i >> 12) & 3, nB = i >> 14;
    int row = nB * 64 + w * 16 + (lane & 15);
    int col = kc * 512 + ks * 32 + (lane >> 4) * 8;
    const float* s = (col < 1024) ? wih + (size_t)row * 1024 + col
                                  : whh + (size_t)row * 1024 + (col - 1024);
    ((uint4*)wpk)[i] = pack8(*(const float4*)s, *(const float4*)(s + 4));
}

// q weights packed: kcN=2, nB<8
__global__ void pack_qw(const float* __restrict__ wq, u16* __restrict__ qpk) {
    int i = blockIdx.x * 256 + threadIdx.x;          // 65536
    int lane = i & 63, ks = (i >> 6) & 15, kc = (i >> 10) & 1, w = (i >> 11) & 3, nB = i >> 13;
    int row = nB * 64 + w * 16 + (lane & 15);
    int col = kc * 512 + ks * 32 + (lane >> 4) * 8;
    const float* s = wq + (size_t)row * 1024 + col;
    ((uint4*)qpk)[i] = pack8(*(const float4*)s, *(const float4*)(s + 4));
}

// stacked K/V projection weights [1024][1024]: rows<512 = wk, else wv
__global__ void stack_kv(const float* __restrict__ wk, const float* __restrict__ wv,
                         u16* __restrict__ dst) {
    int i = blockIdx.x * 256 + threadIdx.x;          // 131072
    int row = i >> 7, k = (i & 127) * 8;
    const float* s = (row < 512) ? wk + (size_t)row * 1024 + k
                                 : wv + (size_t)(row - 512) * 1024 + k;
    ((uint4*)dst)[i] = pack8(*(const float4*)s, *(const float4*)(s + 4));
}
__global__ void stack_bias(const float* __restrict__ bk, const float* __restrict__ bv,
                           float* __restrict__ dst) {
    int i = blockIdx.x * 256 + threadIdx.x;
    if (i < 512) dst[i] = bk[i]; else if (i < 1024) dst[i] = bv[i - 512];
}

__global__ void embed_k(const int* __restrict__ tgt, const float* __restrict__ table,
                        u16* __restrict__ Eb) {
    int bid = blockIdx.x;            // t*64 + b
    int t = bid >> 6, b = bid & 63;
    int tok = (t == 0) ? 0 : tgt[b * TDEC_ + t - 1];
    int lane = threadIdx.x;
    const float* src = table + (size_t)tok * AA + lane * 8;
    ((uint4*)Eb)[(size_t)bid * 64 + lane] = pack8(*(const float4*)src, *(const float4*)(src + 4));
}

// ---------------- big MFMA GEMM: 128x128 tile, XCD-chunked swizzle ----------------
// OUT: 1=bf16+bias, 2=f32+bias w/ (t*64+b)->(b*64+t) remap, 6=bf16+bias split to out/out2
template<int OUT, bool AF32>
__global__ __launch_bounds__(256) void gemm_big(
    const void* __restrict__ Av, int lda,
    const u16* __restrict__ W, int ldw,
    const float* __restrict__ bias,
    void* __restrict__ outv, void* __restrict__ outv2, int ldo, int K) {
    __shared__ u16 As[128 * 128];
    __shared__ u16 Ws[128 * 128];
    const int tid = threadIdx.x;
    const int w = tid >> 6, lane = tid & 63;
    const int wm = w >> 1, wn = w & 1;
    const int li = lane & 15, lg = lane >> 4;
    const int nwg = gridDim.x * gridDim.y;
    const int flat = blockIdx.y * gridDim.x + blockIdx.x;
    const int nf = (flat & 7) * (nwg >> 3) + (flat >> 3);
    const int mB = (nf / gridDim.x) * 128, nB = (nf % gridDim.x) * 128;
    v4f acc[4][4];
    #pragma unroll
    for (int mt = 0; mt < 4; ++mt)
        #pragma unroll
        for (int nt = 0; nt < 4; ++nt) acc[mt][nt] = (v4f){0.f, 0.f, 0.f, 0.f};
    for (int kc = 0; kc < K; kc += 128) {
        for (int it = 0; it < 8; ++it) {
            int flat2 = it * 256 + tid;
            int row = flat2 >> 4, c8 = flat2 & 15;
            uint4 val;
            if (AF32) {
                const float* Af = (const float*)Av + (size_t)(mB + row) * lda + kc + c8 * 8;
                val = pack8(*(const float4*)Af, *(const float4*)(Af + 4));
            } else {
                val = *(const uint4*)((const u16*)Av + (size_t)(mB + row) * lda + kc + c8 * 8);
            }
            int byte = (row * 256 + c8 * 16) ^ ((row & 7) << 4);
            *(uint4*)((char*)As + byte) = val;
            uint4 wv2 = *(const uint4*)(W + (size_t)(nB + row) * ldw + kc + c8 * 8);
            *(uint4*)((char*)Ws + byte) = wv2;
        }
        __syncthreads();
        for (int ks = 0; ks < 4; ++ks) {
            v8s wf[4];
            #pragma unroll
            for (int nt = 0; nt < 4; ++nt) {
                int row = wn * 64 + nt * 16 + li;
                int byte = (row * 256 + ks * 64 + lg * 16) ^ ((row & 7) << 4);
                wf[nt] = *(const v8s*)((char*)Ws + byte);
            }
            #pragma unroll
            for (int mt = 0; mt < 4; ++mt) {
                int row = wm * 64 + mt * 16 + li;
                int byte = (row * 256 + ks * 64 + lg * 16) ^ ((row & 7) << 4);
                v8s af = *(const v8s*)((char*)As + byte);
                #pragma unroll
                for (int nt = 0; nt < 4; ++nt)
                    acc[mt][nt] = __builtin_amdgcn_mfma_f32_16x16x32_bf16(af, wf[nt], acc[mt][nt], 0, 0, 0);
            }
        }
        __syncthreads();
    }
    #pragma unroll
    for (int mt = 0; mt < 4; ++mt) {
        #pragma unroll
        for (int r = 0; r < 4; ++r) {
            int m = mB + wm * 64 + mt * 16 + lg * 4 + r;
            #pragma unroll
            for (int nt = 0; nt < 4; ++nt) {
                int n = nB + wn * 64 + nt * 16 + li;
                float v = acc[mt][nt][r] + bias[n];
                if (OUT == 1) {
                    ((u16*)outv)[(size_t)m * ldo + n] = f2bf(v);
                } else if (OUT == 2) {
                    int mm = (m & 63) * TDEC_ + (m >> 6);
                    ((float*)outv)[(size_t)mm * ldo + n] = v;
                } else {
                    if (n < 512) ((u16*)outv)[(size_t)m * 512 + n] = f2bf(v);
                    else         ((u16*)outv2)[(size_t)m * 512 + (n - 512)] = f2bf(v);
                }
            }
        }
    }
}

// ---------------- per-step MFMA GEMM (K-split, packed W, bf16 partials) ----------------
// gp[(kc*64+m)*N + n] = bf16( sum_{k in chunk kc} A_kc[m][k] * W[n][kc*512+k] )
__global__ __launch_bounds__(256) void gemm_step(
    const u16* A0, const u16* A1, const u16* A2, const u16* A3,
    int l0, int l1, int l2, int l3,
    const u16* __restrict__ wpk, int kcN,
    u16* __restrict__ gp, int N) {
    __shared__ u16 As[64 * 512];
    const int tid = threadIdx.x;
    const int kc = blockIdx.y;
    const u16* A = (kc == 0) ? A0 : (kc == 1) ? A1 : (kc == 2) ? A2 : A3;
    const int lda = (kc == 0) ? l0 : (kc == 1) ? l1 : (kc == 2) ? l2 : l3;
    for (int it = 0; it < 16; ++it) {
        int flat = it * 256 + tid;
        int row = flat >> 6, c8 = flat & 63;
        uint4 v = *(const uint4*)(A + (size_t)row * lda + c8 * 8);
        int byte = (row * 1024 + c8 * 16) ^ ((row & 7) << 4);
        *(uint4*)((char*)As + byte) = v;
    }
    __syncthreads();
    const int w = tid >> 6, lane = tid & 63;
    const int li = lane & 15, lg = lane >> 4;
    const u16* Wp = wpk + (size_t)((blockIdx.x * 4 + w) * kcN + kc) * 8192 + lane * 8;
    v4f acc[4];
    #pragma unroll
    for (int mt = 0; mt < 4; ++mt) acc[mt] = (v4f){0.f, 0.f, 0.f, 0.f};
    for (int ks = 0; ks < 16; ++ks) {
        v8s wf = *(const v8s*)(Wp + ks * 512);
        #pragma unroll
        for (int mt = 0; mt < 4; ++mt) {
            int row = mt * 16 + li;
            int byte = (row * 1024 + ks * 64 + lg * 16) ^ ((row & 7) << 4);
            v8s af = *(const v8s*)((char*)As + byte);
            acc[mt] = __builtin_amdgcn_mfma_f32_16x16x32_bf16(af, wf, acc[mt], 0, 0, 0);
        }
    }
    const int col = blockIdx.x * 64 + w * 16 + li;
    u16* g = gp + (size_t)kc * 64 * N;
    #pragma unroll
    for (int mt = 0; mt < 4; ++mt)
        #pragma unroll
        for (int r = 0; r < 4; ++r)
            g[(size_t)(mt * 16 + lg * 4 + r) * N + col] = f2bf(acc[mt][r]);
}

// ---------------- LSTM cell (sums 4 bf16 K-partials + biases), 2 units/thread ----------------
__global__ void cell_k(const u16* __restrict__ gp, const float* __restrict__ bih,
                       const float* __restrict__ bhh, float* __restrict__ c,
                       u16* __restrict__ h, u16* __restrict__ hAll) {
    int idx2 = blockIdx.x * 256 + threadIdx.x;   // grid 128 -> 32768 = 64*512 pairs
    int b = idx2 >> 9, h2 = (idx2 & 511) * 2;
    float g4[4][2];
    #pragma unroll
    for (int g = 0; g < 4; ++g) {
        int col = g * 1024 + h2;
        float s0 = bih[col] + bhh[col];
        float s1 = bih[col + 1] + bhh[col + 1];
        #pragma unroll
        for (int kc = 0; kc < 4; ++kc) {
            unsigned v = *(const unsigned*)(gp + ((size_t)(kc * 64 + b)) * 4096 + col);
            s0 += bf2f((u16)(v & 0xFFFF));
            s1 += bf2f((u16)(v >> 16));
        }
        g4[g][0] = s0; g4[g][1] = s1;
    }
    int ci = b * 1024 + h2;
    float2 cv = *(float2*)(c + ci);
    float hv[2];
    #pragma unroll
    for (int u = 0; u < 2; ++u) {
        float ii = 1.f / (1.f + expf(-g4[0][u]));
        float ff = 1.f / (1.f + expf(-g4[1][u]));
        float oo = 1.f / (1.f + expf(-g4[3][u]));
        float c2 = ff * ((u == 0) ? cv.x : cv.y) + ii * tanhf(g4[2][u]);
        hv[u] = oo * tanhf(c2);
        if (u == 0) cv.x = c2; else cv.y = c2;
    }
    *(float2*)(c + ci) = cv;
    unsigned hp = (unsigned)f2bf(hv[0]) | ((unsigned)f2bf(hv[1]) << 16);
    *(unsigned*)(h + ci) = hp;
    if (hAll) *(unsigned*)(hAll + ci) = hp;
}

// ---------------- scores (bf16 K): sraw[b][t] = dot(Kb[b,t,:], q[b,:]) ----------------
__global__ __launch_bounds__(256) void scores_k(
    const u16* __restrict__ Kb, const u16* __restrict__ qp,
    const float* __restrict__ bq, float* __restrict__ sraw) {
    __shared__ float qs[AA];
    int b = blockIdx.x, tc = blockIdx.y, tid = threadIdx.x;
    for (int a = tid; a < AA; a += 256)
        qs[a] = bf2f(qp[(size_t)b * AA + a]) + bf2f(qp[(size_t)(64 + b) * AA + a]) + bq[a];
    __syncthreads();
    int w = tid >> 6, lane = tid & 63, lg = lane >> 4, li = lane & 15;
    for (int sub = 0; sub < 4; ++sub) {
        int t = tc * 64 + w * 16 + sub * 4 + lg;
        const u16* kr = Kb + ((size_t)b * TENC_ + t) * AA + li * 32;
        float s = 0.f;
        #pragma unroll
        for (int j = 0; j < 4; ++j) {
            uint4 v = *(const uint4*)(kr + j * 8);
            const u16* pv = (const u16*)&v;
            #pragma unroll
            for (int e = 0; e < 8; ++e) s = fmaf(bf2f(pv[e]), qs[li * 32 + j * 8 + e], s);
        }
        s += __shfl_xor(s, 1); s += __shfl_xor(s, 2);
        s += __shfl_xor(s, 4); s += __shfl_xor(s, 8);
        if (li == 0) sraw[(size_t)b * TENC_ + t] = s;
    }
}

// ---------------- softmax + attn.V (bf16 V) ----------------
__global__ __launch_bounds__(256) void attnout_k(
    const float* __restrict__ sraw, const u16* __restrict__ Vb, u16* __restrict__ attnb) {
    __shared__ float red[256];
    __shared__ float p[TENC_];
    __shared__ float accs[4][128];
    int b = blockIdx.x, a0 = blockIdx.y * 128, tid = threadIdx.x;
    float s0 = sraw[(size_t)b * TENC_ + tid], s1 = sraw[(size_t)b * TENC_ + 256 + tid];
    red[tid] = fmaxf(s0, s1);
    __syncthreads();
    for (int off = 128; off; off >>= 1) {
        if (tid < off) red[tid] = fmaxf(red[tid], red[tid + off]);
        __syncthreads();
    }
    float m = red[0];
    __syncthreads();
    float e0 = expf(s0 - m), e1 = expf(s1 - m);
    red[tid] = e0 + e1;
    __syncthreads();
    for (int off = 128; off; off >>= 1) {
        if (tid < off) red[tid] += red[tid + off];
        __syncthreads();
    }
    float inv = 1.f / red[0];
    p[tid] = e0 * inv; p[tid + 256] = e1 * inv;
    __syncthreads();
    int w = tid >> 6, lane = tid & 63;
    float a0f = 0.f, a1f = 0.f;
    for (int t = w; t < TENC_; t += 4) {
        unsigned v = *(const unsigned*)(Vb + ((size_t)b * TENC_ + t) * AA + a0 + lane * 2);
        float pw = p[t];
        a0f += pw * bf2f((u16)(v & 0xFFFF));
        a1f += pw * bf2f((u16)(v >> 16));
    }
    accs[w][lane * 2] = a0f; accs[w][lane * 2 + 1] = a1f;
    __syncthreads();
    if (tid < 128) {
        float s = accs[0][tid] + accs[1][tid] + accs[2][tid] + accs[3][tid];
        attnb[(size_t)b * AA + a0 + tid] = f2bf(s);
    }
}

// ---------------- LayerNorm+ReLU, bf16 in-place ----------------
__global__ __launch_bounds__(256) void ln_relu_b(u16* __restrict__ x, const float* __restrict__ g,
                                                 const float* __restrict__ bb) {
    int row = blockIdx.x, tid = threadIdx.x;
    u16* xr = x + (size_t)row * 2048;
    __shared__ float red[256];
    uint4 v = *(const uint4*)(xr + tid * 8);
    const u16* pv = (const u16*)&v;
    float lv[8];
    float s = 0.f;
    #pragma unroll
    for (int e = 0; e < 8; ++e) { lv[e] = bf2f(pv[e]); s += lv[e]; }
    red[tid] = s;
    __syncthreads();
    for (int off = 128; off; off >>= 1) {
        if (tid < off) red[tid] += red[tid + off];
        __syncthreads();
    }
    float mu = red[0] * (1.f / 2048.f);
    __syncthreads();
    s = 0.f;
    #pragma unroll
    for (int e = 0; e < 8; ++e) { float d = lv[e] - mu; s += d * d; }
    red[tid] = s;
    __syncthreads();
    for (int off = 128; off; off >>= 1) {
        if (tid < off) red[tid] += red[tid + off];
        __syncthreads();
    }
    float inv = rsqrtf(red[0] * (1.f / 2048.f) + 1e-5f);
    const float4 g1 = *(const float4*)(g + tid * 8), g2 = *(const float4*)(g + tid * 8 + 4);
    const float4 b1 = *(const float4*)(bb + tid * 8), b2 = *(const float4*)(bb + tid * 8 + 4);
    float gv[8] = {g1.x, g1.y, g1.z, g1.w, g2.x, g2.y, g2.z, g2.w};
    float bv[8] = {b1.x, b1.y, b1.z, b1.w, b2.x, b2.y, b2.z, b2.w};
    float o[8];
    #pragma unroll
    for (int e = 0; e < 8; ++e) o[e] = fmaxf((lv[e] - mu) * inv * gv[e] + bv[e], 0.f);
    *(uint4*)(xr + tid * 8) = pack8(make_float4(o[0], o[1], o[2], o[3]),
                                    make_float4(o[4], o[5], o[6], o[7]));
}

// ---------------- loss ----------------
__global__ void ce_loss(const float* __restrict__ logits, const int* __restrict__ target,
                        float* __restrict__ acc) {
    const int r = blockIdx.x;
    const float* row = logits + (size_t)r * VV;
    const int tid = threadIdx.x;
    __shared__ float red[256];
    float lv[4];
    float m = -1e30f;
    #pragma unroll
    for (int i = 0; i < 4; ++i) { lv[i] = row[tid + i * 256]; m = fmaxf(m, lv[i]); }
    red[tid] = m;
    __syncthreads();
    for (int off = 128; off; off >>= 1) {
        if (tid < off) red[tid] = fmaxf(red[tid], red[tid + off]);
        __syncthreads();
    }
    m = red[0];
    __syncthreads();
    float s = 0.f;
    #pragma unroll
    for (int i = 0; i < 4; ++i) s += expf(lv[i] - m);
    red[tid] = s;
    __syncthreads();
    for (int off = 128; off; off >>= 1) {
        if (tid < off) red[tid] += red[tid + off];
        __syncthreads();
    }
    if (tid == 0) {
        const float nll = logf(red[0]) + m - row[target[r]];
        atomicAdd(acc, nll);
    }
}

__global__ void finalize_loss(const float* __restrict__ acc, float* __restrict__ out) {
    out[0] = acc[0] * (1.f / 4096.f);
}

// ---------------- host ----------------
extern "C" void kernel_launch(void* const* d_in, const int* in_sizes, int n_in,
                              void* d_out, int out_size, void* d_ws, size_t ws_size,
                              hipStream_t stream) {
    const float* enc       = (const float*)d_in[0];
    const int*   target    = (const int*)d_in[1];
    const float* emb_table = (const float*)d_in[2];
    const float* att_wq    = (const float*)d_in[3];
    const float* att_bq    = (const float*)d_in[4];
    const float* att_wk    = (const float*)d_in[5];
    const float* att_bk    = (const float*)d_in[6];
    const float* att_wv    = (const float*)d_in[7];
    const float* att_bv    = (const float*)d_in[8];
    const float* w_ih0     = (const float*)d_in[9];
    const float* w_hh0     = (const float*)d_in[10];
    const float* b_ih0     = (const float*)d_in[11];
    const float* b_hh0     = (const float*)d_in[12];
    const float* w_ih1     = (const float*)d_in[13];
    const float* w_hh1     = (const float*)d_in[14];
    const float* b_ih1     = (const float*)d_in[15];
    const float* b_hh1     = (const float*)d_in[16];
    const float* mlp_w1    = (const float*)d_in[17];
    const float* mlp_b1    = (const float*)d_in[18];
    const float* ln_g      = (const float*)d_in[19];
    const float* ln_b      = (const float*)d_in[20];
    const float* mlp_w2    = (const float*)d_in[21];
    const float* mlp_b2    = (const float*)d_in[22];
    float* out = (float*)d_out;
    char* ws = (char*)d_ws;

    size_t off = 0;
    auto alloc = [&](size_t bytes) { size_t o = off; off += (bytes + 255) & ~(size_t)255; return o; };
    u16*   Kb    = (u16*)(ws + alloc((size_t)BQ * TENC_ * AA * 2));
    u16*   Vb    = (u16*)(ws + alloc((size_t)BQ * TENC_ * AA * 2));
    u16*   Eb    = (u16*)(ws + alloc((size_t)TDEC_ * BQ * AA * 2));
    u16*   wpk0  = (u16*)(ws + alloc((size_t)4096 * 2048 * 2));
    u16*   wpk1  = (u16*)(ws + alloc((size_t)4096 * 2048 * 2));
    u16*   qpk   = (u16*)(ws + alloc((size_t)512 * 1024 * 2));
    u16*   wkv   = (u16*)(ws + alloc((size_t)1024 * 1024 * 2));
    float* bkv   = (float*)(ws + alloc(1024 * 4));
    u16*   w1b   = (u16*)(ws + alloc((size_t)2 * VV * HH * 2));
    u16*   w2b   = (u16*)(ws + alloc((size_t)VV * 2 * VV * 2));
    u16*   gp    = (u16*)(ws + alloc((size_t)4 * 64 * 4096 * 2));    // bf16 partials
    u16*   qp    = (u16*)(ws + alloc((size_t)2 * 64 * 512 * 2));     // bf16 partials
    float* sraw  = (float*)(ws + alloc((size_t)BQ * TENC_ * 4));
    u16*   h0b   = (u16*)(ws + alloc((size_t)2 * BQ * HH * 2));      // parity double-buffered
    u16*   h1b   = (u16*)(ws + alloc((size_t)2 * BQ * HH * 2));
    u16*   attnb = (u16*)(ws + alloc((size_t)BQ * AA * 2));
    float* c0    = (float*)(ws + alloc((size_t)BQ * HH * 4));
    float* c1    = (float*)(ws + alloc((size_t)BQ * HH * 4));
    u16*   h1a   = (u16*)(ws + alloc((size_t)TDEC_ * BQ * HH * 2));
    u16*   x1b   = (u16*)(ws + alloc((size_t)TDEC_ * BQ * 2 * VV * 2));
    float* lacc  = (float*)(ws + alloc(256));

    // ---- prologue: weight packing/conversion ----
    pack_g<<<4096, 256, 0, stream>>>(w_ih0, w_hh0, wpk0);
    pack_g<<<4096, 256, 0, stream>>>(w_ih1, w_hh1, wpk1);
    pack_qw<<<256, 256, 0, stream>>>(att_wq, qpk);
    stack_kv<<<512, 256, 0, stream>>>(att_wk, att_wv, wkv);
    stack_bias<<<4, 256, 0, stream>>>(att_bk, att_bv, bkv);
    conv_f2b<<<1024, 256, 0, stream>>>(mlp_w1, w1b, 2 * VV * HH / 8);
    conv_f2b<<<1024, 256, 0, stream>>>(mlp_w2, w2b, VV * 2 * VV / 8);
    embed_k<<<TDEC_ * BQ, 64, 0, stream>>>(target, emb_table, Eb);

    hipMemsetAsync(h0b, 0, (size_t)2 * BQ * HH * 2, stream);
    hipMemsetAsync(h1b, 0, (size_t)2 * BQ * HH * 2, stream);
    hipMemsetAsync(attnb, 0, (size_t)BQ * AA * 2, stream);
    hipMemsetAsync(c0, 0, (size_t)BQ * HH * 4, stream);
    hipMemsetAsync(c1, 0, (size_t)BQ * HH * 4, stream);
    hipMemsetAsync(lacc, 0, 4, stream);

    // merged K/V projection: [32768,1024] = enc @ [wk;wv]^T -> bf16 Kb | Vb
    gemm_big<6, true><<<dim3(8, 256), 256, 0, stream>>>(enc, HH, wkv, HH, bkv, Kb, Vb, 512, HH);

    // ---- recurrence: 7 launches/step ----
    for (int t = 0; t < TDEC_; ++t) {
        const int cur = t & 1, prv = cur ^ 1;
        const u16* h0p = h0b + prv * (BQ * HH);
        u16*       h0c = h0b + cur * (BQ * HH);
        const u16* h1p = h1b + prv * (BQ * HH);
        u16*       h1c = h1b + cur * (BQ * HH);
        const u16* et  = Eb + (size_t)t * BQ * AA;
        gemm_step<<<dim3(64, 4), 256, 0, stream>>>(
            et, attnb, h0p, h0p + 512, AA, AA, HH, HH, wpk0, 4, gp, 4096);
        cell_k<<<128, 256, 0, stream>>>(gp, b_ih0, b_hh0, c0, h0c, nullptr);
        gemm_step<<<dim3(64, 4), 256, 0, stream>>>(
            h0c, h0c + 512, h1p, h1p + 512, HH, HH, HH, HH, wpk1, 4, gp, 4096);
        cell_k<<<128, 256, 0, stream>>>(gp, b_ih1, b_hh1, c1, h1c, h1a + (size_t)t * BQ * HH);
        if (t < TDEC_ - 1) {
            gemm_step<<<dim3(8, 2), 256, 0, stream>>>(
                h1c, h1c + 512, h1c, h1c, HH, HH, HH, HH, qpk, 2, qp, 512);
            scores_k<<<dim3(64, 8), 256, 0, stream>>>(Kb, qp, att_bq, sraw);
            attnout_k<<<dim3(64, 4), 256, 0, stream>>>(sraw, Vb, attnb);
        }
    }

    // ---- batched MLP head ----
    gemm_big<1, false><<<dim3(16, 32), 256, 0, stream>>>(h1a, HH, w1b, HH, mlp_b1, x1b, nullptr, 2 * VV, HH);
    ln_relu_b<<<TDEC_ * BQ, 256, 0, stream>>>(x1b, ln_g, ln_b);
    gemm_big<2, false><<<dim3(8, 32), 256, 0, stream>>>(x1b, 2 * VV, w2b, 2 * VV, mlp_b2, out, nullptr, VV, 2 * VV);

    ce_loss<<<BQ * TDEC_, 256, 0, stream>>>(out, target, lacc);
    finalize_loss<<<1, 1, 0, stream>>>(lacc, out + (size_t)BQ * TDEC_ * VV);
}